// Round 8
// baseline (33.452 us; speedup 1.0000x reference)
//
#include <hip/hip_runtime.h>

// FFT convolution via N = 2^18 = 64 x 4096 Cooley-Tukey, 3 dispatches.
//   n = 4096*n1 + n2, k = k1 + 64*k2.
// ka  : distributed 64-pt column FFT over n1 (+ W_N^{-n2 k1})  -> A1[seq][k1][n2]
//       (8 thr/column, 512-thr blocks; blocks 0..7 fill W4096 table)
// kmid: 128 blocks x 1024 thr. Half 0: fwd 4096-FFT of z-row; half 1: fwd FFT of
//       rir-row (concurrent, own LDS dbufs). LDS swap -> both halves pointwise*1/N
//       + inverse 4096-FFT (+W_N^{+n2 k1}), split stores.       -> D[z][k1][n2]
// kc  : distributed 64-pt inverse column FFT over k1, unpack.   -> out
// No grid barriers (R6: agent-scope barriers thrash cross-XCD L2 -> 75us).

#define NTOT 262144
#define TLEN 131072
#define PI2_N     2.3968449808418217e-5f   /* 2*pi / 262144 */
#define PI2_32768 1.9174759848570515e-4f   /* 2*pi / 32768  */
#define PI2_4096  1.5339807878856412e-3f   /* 2*pi / 4096   */
#define PI2_512   1.2271846303085129e-2f   /* 2*pi / 512    */
#define PI2_64    9.8174770424681039e-2f   /* 2*pi / 64     */
#define LB(i) ((i) + ((i) >> 3))           /* LDS pad */

__device__ __forceinline__ float2 cadd(float2 a, float2 b) { return make_float2(a.x + b.x, a.y + b.y); }
__device__ __forceinline__ float2 csub(float2 a, float2 b) { return make_float2(a.x - b.x, a.y - b.y); }
__device__ __forceinline__ float2 cmul(float2 a, float2 b) {
    return make_float2(a.x * b.x - a.y * b.y, a.x * b.y + a.y * b.x);
}
__device__ __forceinline__ float2 cmulc(float2 a, float2 b) {   // a * conj(b)
    return make_float2(a.x * b.x + a.y * b.y, a.y * b.x - a.x * b.y);
}
__device__ __forceinline__ float2 cexp_(float ang) {
    float s, c;
    __sincosf(ang, &s, &c);
    return make_float2(c, s);
}

template<int SIGN>
__device__ __forceinline__ void dft8(float2 x[8]) {
    const float R2 = 0.70710678118654752f;
    float2 t0 = cadd(x[0], x[4]), t1 = csub(x[0], x[4]);
    float2 t2 = cadd(x[2], x[6]), t3 = csub(x[2], x[6]);
    float2 u0 = cadd(x[1], x[5]), u1 = csub(x[1], x[5]);
    float2 u2 = cadd(x[3], x[7]), u3 = csub(x[3], x[7]);
    float2 it3 = (SIGN > 0) ? make_float2(-t3.y, t3.x) : make_float2(t3.y, -t3.x);
    float2 iu3 = (SIGN > 0) ? make_float2(-u3.y, u3.x) : make_float2(u3.y, -u3.x);
    float2 E0 = cadd(t0, t2), E2 = csub(t0, t2);
    float2 E1 = cadd(t1, it3), E3 = csub(t1, it3);
    float2 O0 = cadd(u0, u2), O2 = csub(u0, u2);
    float2 O1 = cadd(u1, iu3), O3 = csub(u1, iu3);
    float2 iO2 = (SIGN > 0) ? make_float2(-O2.y, O2.x) : make_float2(O2.y, -O2.x);
    float2 w1O1 = (SIGN > 0) ? make_float2(R2 * (O1.x - O1.y), R2 * (O1.y + O1.x))
                             : make_float2(R2 * (O1.x + O1.y), R2 * (O1.y - O1.x));
    float2 w3O3 = (SIGN > 0) ? make_float2(R2 * (-O3.x - O3.y), R2 * (O3.x - O3.y))
                             : make_float2(R2 * (O3.y - O3.x), R2 * (-O3.x - O3.y));
    x[0] = cadd(E0, O0);   x[4] = csub(E0, O0);
    x[1] = cadd(E1, w1O1); x[5] = csub(E1, w1O1);
    x[2] = cadd(E2, iO2);  x[6] = csub(E2, iO2);
    x[3] = cadd(E3, w3O3); x[7] = csub(E3, w3O3);
}

// dft8 with x[4..7] == 0 structurally (reads only x[0..3])
template<int SIGN>
__device__ __forceinline__ void dft8z(float2 x[8]) {
    const float R2 = 0.70710678118654752f;
    float2 x0 = x[0], x1 = x[1], x2 = x[2], x3 = x[3];
    float2 rx2 = (SIGN > 0) ? make_float2(-x2.y, x2.x) : make_float2(x2.y, -x2.x);
    float2 rx3 = (SIGN > 0) ? make_float2(-x3.y, x3.x) : make_float2(x3.y, -x3.x);
    float2 E0 = cadd(x0, x2), E2 = csub(x0, x2);
    float2 E1 = cadd(x0, rx2), E3 = csub(x0, rx2);
    float2 O0 = cadd(x1, x3), O2 = csub(x1, x3);
    float2 O1 = cadd(x1, rx3), O3 = csub(x1, rx3);
    float2 iO2 = (SIGN > 0) ? make_float2(-O2.y, O2.x) : make_float2(O2.y, -O2.x);
    float2 w1O1 = (SIGN > 0) ? make_float2(R2 * (O1.x - O1.y), R2 * (O1.y + O1.x))
                             : make_float2(R2 * (O1.x + O1.y), R2 * (O1.y - O1.x));
    float2 w3O3 = (SIGN > 0) ? make_float2(R2 * (-O3.x - O3.y), R2 * (O3.x - O3.y))
                             : make_float2(R2 * (O3.y - O3.x), R2 * (-O3.x - O3.y));
    x[0] = cadd(E0, O0);   x[4] = csub(E0, O0);
    x[1] = cadd(E1, w1O1); x[5] = csub(E1, w1O1);
    x[2] = cadd(E2, iO2);  x[6] = csub(E2, iO2);
    x[3] = cadd(E3, w3O3); x[7] = csub(E3, w3O3);
}

// twiddle by W4096^(base*i) from table (tab[j] = e^{-2pi i j/4096}); conj for inverse.
template<int SIGN>
__device__ __forceinline__ void twtab(float2 x[8], int base, const float2* __restrict__ tab) {
#pragma unroll
    for (int i = 1; i < 8; ++i) {
        float2 w = tab[base * i];
        x[i] = (SIGN < 0) ? cmul(x[i], w) : cmulc(x[i], w);
    }
}

// 4096-pt radix-8 Stockham FFT, t in [0,512), double-buffered LDS L0/L1.
// Leading __syncthreads covers WAR vs the caller's previous use of L0/L1.
template<int SIGN>
__device__ void fft4096(float2 x[8], int t, float2* L0, float2* L1,
                        const float2* __restrict__ tab) {
    __syncthreads();
    dft8<SIGN>(x);
    twtab<SIGN>(x, t, tab);
#pragma unroll
    for (int i = 0; i < 8; ++i) L0[LB(8 * t + i)] = x[i];
    __syncthreads();
    {
        int q = t & 7, p = t >> 3;
#pragma unroll
        for (int i = 0; i < 8; ++i) x[i] = L0[LB(q + 8 * p + 512 * i)];
        dft8<SIGN>(x);
        twtab<SIGN>(x, 8 * p, tab);
#pragma unroll
        for (int i = 0; i < 8; ++i) L1[LB(q + 64 * p + 8 * i)] = x[i];
    }
    __syncthreads();
    {
        int q = t & 63, p = t >> 6;
#pragma unroll
        for (int i = 0; i < 8; ++i) x[i] = L1[LB(q + 64 * p + 512 * i)];
        dft8<SIGN>(x);
        twtab<SIGN>(x, 64 * p, tab);
#pragma unroll
        for (int i = 0; i < 8; ++i) L0[LB(q + 512 * p + 64 * i)] = x[i];
    }
    __syncthreads();
#pragma unroll
    for (int i = 0; i < 8; ++i) x[i] = L0[LB(t + 512 * i)];
    dft8<SIGN>(x);
}

// ka: 192 blocks x 512. Distributed 64-pt column FFT (8 thr/col, 64 cols/block).
__global__ void __launch_bounds__(512) ka(const float* __restrict__ audio,
                                          const float* __restrict__ rir,
                                          float2* __restrict__ A1,
                                          float2* __restrict__ tab) {
    __shared__ float2 Lsh[64 * 73];
    const int bid = blockIdx.x;
    const int tid = threadIdx.x;
    const int t = tid & 7;
    const int c = tid >> 3;

    if (bid < 8)                          // fill W4096 table (read by kmid/kc next)
        tab[bid * 512 + tid] = cexp_(-PI2_4096 * (float)(bid * 512 + tid));

    int seq = bid >> 6;
    int n2 = ((bid & 63) << 6) + c;
    float2 g[8];
    if (seq < 2) {
        const float* c0 = audio + (size_t)(2 * seq) * TLEN;
        const float* c1 = c0 + TLEN;
#pragma unroll
        for (int i = 0; i < 4; ++i) {
            int n = ((t + 8 * i) << 12) + n2;          // n1 = t+8i < 32 (nonzero half)
            g[i] = make_float2(c0[n], c1[n]);
        }
    } else {
#pragma unroll
        for (int i = 0; i < 4; ++i) {
            int n = ((t + 8 * i) << 12) + n2;
            g[i] = make_float2(rir[TLEN - 1 - n], 0.f);
        }
    }
    dft8z<-1>(g);
#pragma unroll
    for (int i = 1; i < 8; ++i)
        g[i] = cmul(g[i], cexp_(-PI2_64 * (float)(t * i)));
    float2* col = Lsh + (size_t)c * 73;
#pragma unroll
    for (int i = 0; i < 8; ++i) col[t + 8 * i] = g[i];
    __syncthreads();
#pragma unroll
    for (int i = 0; i < 8; ++i) g[i] = col[8 * t + i];
    dft8<-1>(g);
    // W_N^{-n2*(8i+t)} = W_N^{-n2 t} * (W_N^{-8 n2})^i  (2 sincos + chain)
    float2 w  = cexp_(-PI2_N * (float)(n2 * t));
    float2 st = cexp_(-PI2_32768 * (float)n2);
    float2* dst = A1 + ((size_t)seq << 18) + n2;
#pragma unroll
    for (int i = 0; i < 8; ++i) {
        dst[(size_t)(8 * i + t) << 12] = cmul(g[i], w);   // k1 = rev8(8t+i) = 8i+t
        w = cmul(w, st);
    }
}

// kmid: 128 blocks x 1024. half 0 -> z-row (bid), half 1 -> rir-row (128 + (bid&63)).
// Concurrent fwd FFTs in separate LDS dbufs, swap spectra, both halves do
// pointwise*1/N + inverse FFT, split stores.
__global__ void __launch_bounds__(1024) kmid(const float2* __restrict__ A1,
                                             float2* __restrict__ D,
                                             const float2* __restrict__ tab) {
    __shared__ float2 Lsh[4 * 4608];       // 147456 B: [half][2][4608]
    const int tid = threadIdx.x;
    const int half = tid >> 9;
    const int t = tid & 511;
    const int k1 = blockIdx.x & 63;

    float2* L0 = Lsh + (size_t)half * 9216;
    float2* L1 = L0 + 4608;
    float2* OL = Lsh + (size_t)(half ^ 1) * 9216;   // other half's L0

    const size_t row = half ? (size_t)(128 + k1) : (size_t)blockIdx.x;
    const float2* src = A1 + (row << 12);
    float2 x[8];
#pragma unroll
    for (int i = 0; i < 8; ++i) x[i] = src[t + 512 * i];

    fft4096<-1>(x, t, L0, L1, tab);

    // swap spectra between halves via L0
    __syncthreads();
#pragma unroll
    for (int i = 0; i < 8; ++i) L0[LB(t + 512 * i)] = x[i];
    __syncthreads();
    float2 o[8];
#pragma unroll
    for (int i = 0; i < 8; ++i) o[i] = OL[LB(t + 512 * i)];

    const float invN = 3.814697265625e-6f;  // 1/262144
#pragma unroll
    for (int i = 0; i < 8; ++i) {
        float2 zz = half ? o[i] : x[i];
        float2 rr = half ? x[i] : o[i];
        float2 y = cmul(zz, rr);
        x[i] = make_float2(y.x * invN, y.y * invN);
    }

    fft4096<1>(x, t, L0, L1, tab);

    // W_N^{+n2 k1}, n2 = t+512i: chain from W_N^{t k1}, step W_512^{k1}
    float2 w  = cexp_(PI2_N * (float)(t * k1));
    float2 st = cexp_(PI2_512 * (float)k1);
    float2* d = D + ((size_t)blockIdx.x << 12) + t;
#pragma unroll
    for (int i = 0; i < 8; ++i) {
        if ((i >> 2) == half) d[512 * i] = cmul(x[i], w);   // wave-uniform split
        w = cmul(w, st);
    }
}

// kc: 128 blocks x 512. Distributed 64-pt inverse column FFT over k1 + unpack.
__global__ void __launch_bounds__(512) kc(const float2* __restrict__ D,
                                          float* __restrict__ out, int Lout,
                                          const float2* __restrict__ tab) {
    __shared__ float2 Lsh[64 * 73];
    const int bid = blockIdx.x;
    const int tid = threadIdx.x;
    const int t = tid & 7;
    const int c = tid >> 3;
    int z = bid >> 6;
    int n2 = ((bid & 63) << 6) + c;

    const float2* src = D + ((size_t)z << 18) + n2;
    float2 g[8];
#pragma unroll
    for (int i = 0; i < 8; ++i)
        g[i] = src[(size_t)(8 * i + t) << 12];          // input[k1=8i+t] -> phys x[8t+i]
    dft8<1>(g);
#pragma unroll
    for (int i = 1; i < 8; ++i)
        g[i] = cmulc(g[i], tab[64 * t * i]);            // W64^{+ti} = conj(tab[64 t i])
    float2* col = Lsh + (size_t)c * 73;
#pragma unroll
    for (int i = 0; i < 8; ++i) col[8 * t + i] = g[i];
    __syncthreads();
#pragma unroll
    for (int i = 0; i < 8; ++i) g[i] = col[t + 8 * i];
    dft8<1>(g);
    float* o0 = out + (size_t)(2 * z) * Lout;
    float* o1 = o0 + Lout;
#pragma unroll
    for (int i = 0; i < 8; ++i) {
        int n = ((t + 8 * i) << 12) + n2;               // n1 = t+8i natural
        if (n < Lout) { o0[n] = g[i].x; o1[n] = g[i].y; }
    }
}

extern "C" void kernel_launch(void* const* d_in, const int* in_sizes, int n_in,
                              void* d_out, int out_size, void* d_ws, size_t ws_size,
                              hipStream_t stream) {
    const float* audio = (const float*)d_in[0];   // (1, 4, T) f32
    const float* rir   = (const float*)d_in[1];   // (T,) f32
    float* out = (float*)d_out;                   // (1, 4, 2T-1) f32
    int Lout = out_size / 4;                      // 262143

    float2* A1  = (float2*)d_ws;                  // 3 * 2^18 complex
    float2* D   = A1 + 3 * NTOT;                  // 2 * 2^18 complex
    float2* tab = D + 2 * NTOT;                   // 4096 complex (32 KB)

    ka  <<<192, 512,  0, stream>>>(audio, rir, A1, tab);
    kmid<<<128, 1024, 0, stream>>>(A1, D, tab);
    kc  <<<128, 512,  0, stream>>>(D, out, Lout, tab);
}